// Round 1
// baseline (766.767 us; speedup 1.0000x reference)
//
#include <hip/hip_runtime.h>
#include <hip/hip_bf16.h>

#define BB 4
#define CC 2048
#define DD 1024
#define HH 16
#define HDD 64

typedef __attribute__((ext_vector_type(8))) short bf16x8;
typedef __attribute__((ext_vector_type(4))) float f32x4;
typedef __attribute__((ext_vector_type(4))) unsigned short ushort4_t;

// (1/sqrt(64)) * log2(e): puts scores directly in exp2 domain
#define SCALE_LOG2E 0.18033688011112042f

__device__ __forceinline__ unsigned short f2bf(float f) {
  union { float f; unsigned u; } v; v.f = f;
  unsigned u = v.u;
  return (unsigned short)((u + 0x7fffu + ((u >> 16) & 1u)) >> 16);
}

// ---------------------------------------------------------------------------
// Kernel 1: per-head QKV projection.
// q,k stored [B,H,C,HD] bf16 (q pre-scaled by SCALE_LOG2E); v stored
// transposed [B,H,HD,C] bf16 so PV B-operand reads are contiguous.
// ---------------------------------------------------------------------------
__global__ __launch_bounds__(256) void qkv_proj_kernel(
    const float* __restrict__ x,
    const float* __restrict__ Wq, const float* __restrict__ bq,
    const float* __restrict__ Wk, const float* __restrict__ bk,
    const float* __restrict__ Wv, const float* __restrict__ bv,
    unsigned short* __restrict__ qo, unsigned short* __restrict__ ko,
    unsigned short* __restrict__ vto)
{
  const int blk = blockIdx.x;          // B*H*(C/128) = 1024
  const int ct = blk & 15;
  const int h  = (blk >> 4) & 15;
  const int b  = blk >> 8;
  const int wave = threadIdx.x >> 6;
  const int lane = threadIdx.x & 63;
  const int g = lane >> 4, l15 = lane & 15;

  const float* wqh = Wq + h * HDD * HDD;
  const float* wkh = Wk + h * HDD * HDD;
  const float* wvh = Wv + h * HDD * HDD;

  // B-fragments of the three weight matrices: col e = 16n+l15, k = 32c+8g+i
  bf16x8 wqf[2][4], wkf[2][4], wvf[2][4];
  for (int c = 0; c < 2; ++c)
    for (int n = 0; n < 4; ++n) {
      const int e = 16 * n + l15;
      const int d0 = 32 * c + 8 * g;
      bf16x8 tq, tk, tv;
      for (int i = 0; i < 8; ++i) {
        tq[i] = (short)f2bf(wqh[(d0 + i) * HDD + e]);
        tk[i] = (short)f2bf(wkh[(d0 + i) * HDD + e]);
        tv[i] = (short)f2bf(wvh[(d0 + i) * HDD + e]);
      }
      wqf[c][n] = tq; wkf[c][n] = tk; wvf[c][n] = tv;
    }
  float bqv[4], bkv[4], bvv[4];
  for (int n = 0; n < 4; ++n) {
    bqv[n] = bq[h * HDD + 16 * n + l15];
    bkv[n] = bk[h * HDD + 16 * n + l15];
    bvv[n] = bv[h * HDD + 16 * n + l15];
  }

  const f32x4 fzero = {0.f, 0.f, 0.f, 0.f};
  const int c0 = ct * 128 + wave * 32;      // this wave covers 32 rows
  const int bh = b * HH + h;

  for (int mt = 0; mt < 2; ++mt) {
    const int crow_a = c0 + mt * 16 + l15;  // A-frag row
    bf16x8 xa[2];
    for (int c = 0; c < 2; ++c) {
      const float* xp = x + (size_t)(b * CC + crow_a) * DD + h * HDD + 32 * c + 8 * g;
      bf16x8 t;
      for (int i = 0; i < 8; ++i) t[i] = (short)f2bf(xp[i]);
      xa[c] = t;
    }
    f32x4 aq[4] = {fzero, fzero, fzero, fzero};
    f32x4 ak[4] = {fzero, fzero, fzero, fzero};
    f32x4 av[4] = {fzero, fzero, fzero, fzero};
    for (int c = 0; c < 2; ++c)
      for (int n = 0; n < 4; ++n) {
        aq[n] = __builtin_amdgcn_mfma_f32_16x16x32_bf16(xa[c], wqf[c][n], aq[n], 0, 0, 0);
        ak[n] = __builtin_amdgcn_mfma_f32_16x16x32_bf16(xa[c], wkf[c][n], ak[n], 0, 0, 0);
        av[n] = __builtin_amdgcn_mfma_f32_16x16x32_bf16(xa[c], wvf[c][n], av[n], 0, 0, 0);
      }
    const int crow_d = c0 + mt * 16 + 4 * g;  // D rows = crow_d + reg
    for (int n = 0; n < 4; ++n) {
      const int e = 16 * n + l15;
      ushort4_t vpack;
      for (int r = 0; r < 4; ++r) {
        const int cr = crow_d + r;
        qo[((size_t)bh * CC + cr) * HDD + e] = f2bf((aq[n][r] + bqv[n]) * SCALE_LOG2E);
        ko[((size_t)bh * CC + cr) * HDD + e] = f2bf(ak[n][r] + bkv[n]);
        vpack[r] = f2bf(av[n][r] + bvv[n]);
      }
      *(ushort4_t*)(vto + ((size_t)bh * HDD + e) * CC + crow_d) = vpack;
    }
  }
}

// ---------------------------------------------------------------------------
// Kernel 2: flash attention forward (out + LSE). One wave owns 16 q-rows;
// K / V^T fragments read straight from global (L1/L2 resident, 256KB/head).
// P goes D-layout -> A-layout through a swizzled per-wave LDS bounce.
// ---------------------------------------------------------------------------
__global__ __launch_bounds__(256) void flash_fwd_kernel(
    const unsigned short* __restrict__ qw, const unsigned short* __restrict__ kw,
    const unsigned short* __restrict__ vtw,
    float* __restrict__ out, float* __restrict__ lse)
{
  __shared__ unsigned short plds[4][16 * 64];
  const int blk = blockIdx.x;          // B*H*(C/64) = 2048
  const int qt = blk & 31;
  const int h  = (blk >> 5) & 15;
  const int b  = blk >> 9;
  const int wave = threadIdx.x >> 6;
  const int lane = threadIdx.x & 63;
  const int g = lane >> 4, l15 = lane & 15;
  const int bh = b * HH + h;
  const int q0 = qt * 64 + wave * 16;

  const unsigned short* qbh = qw + (size_t)bh * CC * HDD;
  const unsigned short* kbh = kw + (size_t)bh * CC * HDD;
  const unsigned short* vbh = vtw + (size_t)bh * HDD * CC;

  bf16x8 qa[2];
  for (int c = 0; c < 2; ++c)
    qa[c] = *(const bf16x8*)(qbh + (q0 + l15) * HDD + 32 * c + 8 * g);

  const f32x4 fzero = {0.f, 0.f, 0.f, 0.f};
  f32x4 acc[4] = {fzero, fzero, fzero, fzero};
  float m[4], l[4];
  for (int r = 0; r < 4; ++r) { m[r] = -1e30f; l[r] = 0.f; }

  unsigned short* myp = plds[wave];

  for (int kt = 0; kt < 32; ++kt) {
    const int kv0 = kt * 64;
    f32x4 s[4] = {fzero, fzero, fzero, fzero};
    for (int c = 0; c < 2; ++c)
      for (int n = 0; n < 4; ++n) {
        bf16x8 kf = *(const bf16x8*)(kbh + (kv0 + 16 * n + l15) * HDD + 32 * c + 8 * g);
        s[n] = __builtin_amdgcn_mfma_f32_16x16x32_bf16(qa[c], kf, s[n], 0, 0, 0);
      }
    // online softmax: rows are q = 4g+r; reduce across the 16 l15-lanes
    float sc[4];
    for (int r = 0; r < 4; ++r) {
      float rm = fmaxf(fmaxf(s[0][r], s[1][r]), fmaxf(s[2][r], s[3][r]));
      for (int d = 1; d < 16; d <<= 1) rm = fmaxf(rm, __shfl_xor(rm, d, 64));
      const float mn = fmaxf(m[r], rm);
      sc[r] = __builtin_amdgcn_exp2f(m[r] - mn);
      m[r] = mn;
    }
    float rs[4] = {0.f, 0.f, 0.f, 0.f};
    for (int n = 0; n < 4; ++n)
      for (int r = 0; r < 4; ++r) {
        const float p = __builtin_amdgcn_exp2f(s[n][r] - m[r]);
        rs[r] += p;
        const int qq = 4 * g + r;
        myp[qq * 64 + ((16 * n + l15) ^ ((qq & 7) << 3))] = f2bf(p);
      }
    for (int r = 0; r < 4; ++r) {
      for (int d = 1; d < 16; d <<= 1) rs[r] += __shfl_xor(rs[r], d, 64);
      l[r] = l[r] * sc[r] + rs[r];
    }
    for (int n = 0; n < 4; ++n)
      for (int r = 0; r < 4; ++r) acc[n][r] *= sc[r];
    // P A-fragments back from LDS (swizzle-matched, 16B reads)
    bf16x8 pa[2];
    for (int c = 0; c < 2; ++c)
      pa[c] = *(const bf16x8*)(myp + l15 * 64 + ((32 * c + 8 * g) ^ ((l15 & 7) << 3)));
    for (int c = 0; c < 2; ++c)
      for (int n = 0; n < 4; ++n) {
        bf16x8 vf = *(const bf16x8*)(vbh + (16 * n + l15) * CC + kv0 + 32 * c + 8 * g);
        acc[n] = __builtin_amdgcn_mfma_f32_16x16x32_bf16(pa[c], vf, acc[n], 0, 0, 0);
      }
  }

  float rcpl[4];
  for (int r = 0; r < 4; ++r) rcpl[r] = __builtin_amdgcn_rcpf(l[r]);
  for (int n = 0; n < 4; ++n)
    for (int r = 0; r < 4; ++r) {
      const int cr = q0 + 4 * g + r;
      out[(size_t)(b * CC + cr) * DD + h * HDD + 16 * n + l15] = acc[n][r] * rcpl[r];
    }
  if (l15 == 0)
    for (int r = 0; r < 4; ++r)
      lse[(size_t)bh * CC + q0 + 4 * g + r] =
          m[r] + __builtin_amdgcn_logf(l[r]) + 4.0f;  // + log2(H)
}

// ---------------------------------------------------------------------------
// Kernel 3: attn_mean = (1/H) * sum_h softmax_h  (1/H folded into lse).
// Recomputes S per head via MFMA; accumulates over heads in registers.
// ---------------------------------------------------------------------------
__global__ __launch_bounds__(256) void attn_mean_kernel(
    const unsigned short* __restrict__ qw, const unsigned short* __restrict__ kw,
    const float* __restrict__ lse, float* __restrict__ amean)
{
  const int blk = blockIdx.x;          // B * (C/64) * 4 = 512
  const int ks = blk & 3;
  const int qt = (blk >> 2) & 31;
  const int b  = blk >> 7;
  const int wave = threadIdx.x >> 6;
  const int lane = threadIdx.x & 63;
  const int g = lane >> 4, l15 = lane & 15;
  const int q0 = qt * 64 + wave * 16;
  const f32x4 fzero = {0.f, 0.f, 0.f, 0.f};

  for (int kt = ks * 8; kt < ks * 8 + 8; ++kt) {
    const int kv0 = kt * 64;
    f32x4 ap[4] = {fzero, fzero, fzero, fzero};
    for (int h = 0; h < HH; ++h) {
      const int bh = b * HH + h;
      const unsigned short* qbh = qw + (size_t)bh * CC * HDD;
      const unsigned short* kbh = kw + (size_t)bh * CC * HDD;
      bf16x8 qa[2];
      for (int c = 0; c < 2; ++c)
        qa[c] = *(const bf16x8*)(qbh + (q0 + l15) * HDD + 32 * c + 8 * g);
      float ls[4];
      for (int r = 0; r < 4; ++r) ls[r] = lse[(size_t)bh * CC + q0 + 4 * g + r];
      f32x4 s[4] = {fzero, fzero, fzero, fzero};
      for (int c = 0; c < 2; ++c)
        for (int n = 0; n < 4; ++n) {
          bf16x8 kf = *(const bf16x8*)(kbh + (kv0 + 16 * n + l15) * HDD + 32 * c + 8 * g);
          s[n] = __builtin_amdgcn_mfma_f32_16x16x32_bf16(qa[c], kf, s[n], 0, 0, 0);
        }
      for (int n = 0; n < 4; ++n)
        for (int r = 0; r < 4; ++r)
          ap[n][r] += __builtin_amdgcn_exp2f(s[n][r] - ls[r]);
    }
    for (int n = 0; n < 4; ++n)
      for (int r = 0; r < 4; ++r)
        amean[(size_t)(b * CC + q0 + 4 * g + r) * CC + kv0 + 16 * n + l15] = ap[n][r];
  }
}

extern "C" void kernel_launch(void* const* d_in, const int* in_sizes, int n_in,
                              void* d_out, int out_size, void* d_ws, size_t ws_size,
                              hipStream_t stream) {
  const float* x  = (const float*)d_in[0];
  const float* Wq = (const float*)d_in[1];
  const float* bq = (const float*)d_in[2];
  const float* Wk = (const float*)d_in[3];
  const float* bk = (const float*)d_in[4];
  const float* Wv = (const float*)d_in[5];
  const float* bv = (const float*)d_in[6];
  float* out = (float*)d_out;
  float* amean = out + (size_t)BB * CC * DD;

  const size_t nqkv = (size_t)BB * HH * CC * HDD;
  unsigned short* qws  = (unsigned short*)d_ws;
  unsigned short* kws  = qws + nqkv;
  unsigned short* vtws = kws + nqkv;
  float* lse = (float*)(vtws + nqkv);

  qkv_proj_kernel<<<BB * HH * (CC / 128), 256, 0, stream>>>(
      x, Wq, bq, Wk, bk, Wv, bv, qws, kws, vtws);
  flash_fwd_kernel<<<BB * HH * (CC / 64), 256, 0, stream>>>(
      qws, kws, vtws, out, lse);
  attn_mean_kernel<<<BB * (CC / 64) * 4, 256, 0, stream>>>(
      qws, kws, lse, amean);
}

// Round 2
// 735.579 us; speedup vs baseline: 1.0424x; 1.0424x over previous
//
#include <hip/hip_runtime.h>
#include <hip/hip_bf16.h>

#define BB 4
#define CC 2048
#define DD 1024
#define HH 16
#define HDD 64

typedef __attribute__((ext_vector_type(8))) short bf16x8;
typedef __attribute__((ext_vector_type(4))) float f32x4;
typedef __attribute__((ext_vector_type(4))) unsigned short ushort4_t;

// (1/sqrt(64)) * log2(e): puts scores directly in exp2 domain
#define SCALE_LOG2E 0.18033688011112042f

__device__ __forceinline__ unsigned short f2bf(float f) {
  union { float f; unsigned u; } v; v.f = f;
  unsigned u = v.u;
  return (unsigned short)((u + 0x7fffu + ((u >> 16) & 1u)) >> 16);
}

__device__ __forceinline__ unsigned cvt_pk_bf16(float lo, float hi) {
  unsigned r;
  asm volatile("v_cvt_pk_bf16_f32 %0, %1, %2" : "=v"(r) : "v"(lo), "v"(hi));
  return r;
}

// ---------------------------------------------------------------------------
// Kernel 1: per-head QKV projection.
// q,k stored [B,H,C,HD] bf16 (q pre-scaled by SCALE_LOG2E); v stored
// transposed [B,H,HD,C] bf16 so PV B-operand reads are contiguous.
// ---------------------------------------------------------------------------
__global__ __launch_bounds__(256) void qkv_proj_kernel(
    const float* __restrict__ x,
    const float* __restrict__ Wq, const float* __restrict__ bq,
    const float* __restrict__ Wk, const float* __restrict__ bk,
    const float* __restrict__ Wv, const float* __restrict__ bv,
    unsigned short* __restrict__ qo, unsigned short* __restrict__ ko,
    unsigned short* __restrict__ vto)
{
  const int blk = blockIdx.x;          // B*H*(C/128) = 1024
  const int ct = blk & 15;
  const int h  = (blk >> 4) & 15;
  const int b  = blk >> 8;
  const int wave = threadIdx.x >> 6;
  const int lane = threadIdx.x & 63;
  const int g = lane >> 4, l15 = lane & 15;

  const float* wqh = Wq + h * HDD * HDD;
  const float* wkh = Wk + h * HDD * HDD;
  const float* wvh = Wv + h * HDD * HDD;

  // B-fragments of the three weight matrices: col e = 16n+l15, k = 32c+8g+i
  bf16x8 wqf[2][4], wkf[2][4], wvf[2][4];
  for (int c = 0; c < 2; ++c)
    for (int n = 0; n < 4; ++n) {
      const int e = 16 * n + l15;
      const int d0 = 32 * c + 8 * g;
      bf16x8 tq, tk, tv;
      for (int i = 0; i < 8; ++i) {
        tq[i] = (short)f2bf(wqh[(d0 + i) * HDD + e]);
        tk[i] = (short)f2bf(wkh[(d0 + i) * HDD + e]);
        tv[i] = (short)f2bf(wvh[(d0 + i) * HDD + e]);
      }
      wqf[c][n] = tq; wkf[c][n] = tk; wvf[c][n] = tv;
    }
  float bqv[4], bkv[4], bvv[4];
  for (int n = 0; n < 4; ++n) {
    bqv[n] = bq[h * HDD + 16 * n + l15];
    bkv[n] = bk[h * HDD + 16 * n + l15];
    bvv[n] = bv[h * HDD + 16 * n + l15];
  }

  const f32x4 fzero = {0.f, 0.f, 0.f, 0.f};
  const int c0 = ct * 128 + wave * 32;      // this wave covers 32 rows
  const int bh = b * HH + h;

  for (int mt = 0; mt < 2; ++mt) {
    const int crow_a = c0 + mt * 16 + l15;  // A-frag row
    bf16x8 xa[2];
    for (int c = 0; c < 2; ++c) {
      const f32x4* xp = (const f32x4*)(x + (size_t)(b * CC + crow_a) * DD + h * HDD + 32 * c + 8 * g);
      f32x4 x0 = xp[0], x1 = xp[1];
      bf16x8 t;
      for (int i = 0; i < 4; ++i) { t[i] = (short)f2bf(x0[i]); t[4 + i] = (short)f2bf(x1[i]); }
      xa[c] = t;
    }
    f32x4 aq[4] = {fzero, fzero, fzero, fzero};
    f32x4 ak[4] = {fzero, fzero, fzero, fzero};
    f32x4 av[4] = {fzero, fzero, fzero, fzero};
    for (int c = 0; c < 2; ++c)
      for (int n = 0; n < 4; ++n) {
        aq[n] = __builtin_amdgcn_mfma_f32_16x16x32_bf16(xa[c], wqf[c][n], aq[n], 0, 0, 0);
        ak[n] = __builtin_amdgcn_mfma_f32_16x16x32_bf16(xa[c], wkf[c][n], ak[n], 0, 0, 0);
        av[n] = __builtin_amdgcn_mfma_f32_16x16x32_bf16(xa[c], wvf[c][n], av[n], 0, 0, 0);
      }
    const int crow_d = c0 + mt * 16 + 4 * g;  // D rows = crow_d + reg
    for (int n = 0; n < 4; ++n) {
      const int e = 16 * n + l15;
      ushort4_t vpack;
      for (int r = 0; r < 4; ++r) {
        const int cr = crow_d + r;
        qo[((size_t)bh * CC + cr) * HDD + e] = f2bf((aq[n][r] + bqv[n]) * SCALE_LOG2E);
        ko[((size_t)bh * CC + cr) * HDD + e] = f2bf(ak[n][r] + bkv[n]);
        vpack[r] = f2bf(av[n][r] + bvv[n]);
      }
      *(ushort4_t*)(vto + ((size_t)bh * HDD + e) * CC + crow_d) = vpack;
    }
  }
}

// ---------------------------------------------------------------------------
// Kernel 2: flash attention forward (out + LSE), SWAPPED QK^T.
// s = mfma(K, Q) so each lane owns q-row (q0+l15): the kv-tile row max/sum
// are lane-local over 16 regs + two shfl_xor across the 4 g-groups.
// P packed via v_cvt_pk_bf16_f32, bounced through swizzled LDS (b64 writes,
// b128 reads), PV in the original orientation. V prefetched to regs before
// the softmax so its latency hides under the VALU work. Defer-max (THR=8).
// ---------------------------------------------------------------------------
__global__ __launch_bounds__(256) void flash_fwd_kernel(
    const unsigned short* __restrict__ qw, const unsigned short* __restrict__ kw,
    const unsigned short* __restrict__ vtw,
    float* __restrict__ out, float* __restrict__ lse)
{
  __shared__ __align__(16) unsigned short plds[4][16 * 64];
  const int blk = blockIdx.x;          // B*H*(C/64) = 2048
  const int qt = blk & 31;
  const int h  = (blk >> 5) & 15;
  const int b  = blk >> 9;
  const int wave = threadIdx.x >> 6;
  const int lane = threadIdx.x & 63;
  const int g = lane >> 4, l15 = lane & 15;
  const int bh = b * HH + h;
  const int q0 = qt * 64 + wave * 16;

  const unsigned short* qbh = qw + (size_t)bh * CC * HDD;
  const unsigned short* kbh = kw + (size_t)bh * CC * HDD;
  const unsigned short* vbh = vtw + (size_t)bh * HDD * CC;

  // Q as B-operand: col = q0+l15, k = d = 32c+8g+i
  bf16x8 qb[2];
  for (int c = 0; c < 2; ++c)
    qb[c] = *(const bf16x8*)(qbh + (q0 + l15) * HDD + 32 * c + 8 * g);

  const f32x4 fzero = {0.f, 0.f, 0.f, 0.f};
  f32x4 acc[4] = {fzero, fzero, fzero, fzero};  // acc[n][r] = out[q0+4g+r][e=16n+l15]
  float m = -1e30f, l = 0.f;                    // softmax state for q = q0 + l15
  const int swz = (l15 & 7) << 3;               // LDS swizzle (ushort units)
  unsigned short* myp = plds[wave];

  for (int kt = 0; kt < 32; ++kt) {
    const int kv0 = kt * 64;
    // S^T tile: A = K (row = kv = 16n+l15), B = Q  -> s[n][r]: kv=16n+4g+r, q=q0+l15
    f32x4 s[4] = {fzero, fzero, fzero, fzero};
    for (int c = 0; c < 2; ++c)
      for (int n = 0; n < 4; ++n) {
        bf16x8 kf = *(const bf16x8*)(kbh + (kv0 + 16 * n + l15) * HDD + 32 * c + 8 * g);
        s[n] = __builtin_amdgcn_mfma_f32_16x16x32_bf16(kf, qb[c], s[n], 0, 0, 0);
      }
    // prefetch V fragments for this tile (independent of softmax)
    bf16x8 vf[2][4];
    for (int c = 0; c < 2; ++c)
      for (int n = 0; n < 4; ++n)
        vf[c][n] = *(const bf16x8*)(vbh + (16 * n + l15) * CC + kv0 + 32 * c + 8 * g);

    // lane-local row max over 16 regs, then reduce across the 4 g-groups
    float pm = s[0][0];
    for (int n = 0; n < 4; ++n)
      for (int r = 0; r < 4; ++r) pm = fmaxf(pm, s[n][r]);
    pm = fmaxf(pm, __shfl_xor(pm, 16, 64));
    pm = fmaxf(pm, __shfl_xor(pm, 32, 64));

    float mn = fmaxf(m, pm);
    const bool keep = __all(mn - m <= 8.0f);   // defer-max (T13)
    if (keep) mn = m;

    float rs = 0.f;
    for (int n = 0; n < 4; ++n) {
      float p0 = __builtin_amdgcn_exp2f(s[n][0] - mn);
      float p1 = __builtin_amdgcn_exp2f(s[n][1] - mn);
      float p2 = __builtin_amdgcn_exp2f(s[n][2] - mn);
      float p3 = __builtin_amdgcn_exp2f(s[n][3] - mn);
      rs += (p0 + p1) + (p2 + p3);
      unsigned w0 = cvt_pk_bf16(p0, p1);
      unsigned w1 = cvt_pk_bf16(p2, p3);
      // P[q=l15][kv=16n+4g + r], swizzled, 8B write
      uint2 wv; wv.x = w0; wv.y = w1;
      *(uint2*)(myp + l15 * 64 + ((16 * n + 4 * g) ^ swz)) = wv;
    }
    rs += __shfl_xor(rs, 16, 64);
    rs += __shfl_xor(rs, 32, 64);

    if (keep) {
      l += rs;
    } else {
      const float sc = __builtin_amdgcn_exp2f(m - mn);
      l = l * sc + rs;
      m = mn;
      float scr[4];
      for (int r = 0; r < 4; ++r) scr[r] = __shfl(sc, 4 * g + r, 64);
      for (int n = 0; n < 4; ++n)
        for (int r = 0; r < 4; ++r) acc[n][r] *= scr[r];
    }

    // P A-fragments back from LDS (swizzle-matched, 16B reads)
    bf16x8 pa[2];
    for (int c = 0; c < 2; ++c)
      pa[c] = *(const bf16x8*)(myp + l15 * 64 + ((32 * c + 8 * g) ^ swz));
    for (int c = 0; c < 2; ++c)
      for (int n = 0; n < 4; ++n)
        acc[n] = __builtin_amdgcn_mfma_f32_16x16x32_bf16(pa[c], vf[c][n], acc[n], 0, 0, 0);
  }

  float rl = __builtin_amdgcn_rcpf(l);       // for q = q0 + l15
  float rlr[4];
  for (int r = 0; r < 4; ++r) rlr[r] = __shfl(rl, 4 * g + r, 64);
  for (int n = 0; n < 4; ++n)
    for (int r = 0; r < 4; ++r) {
      const int cr = q0 + 4 * g + r;
      out[(size_t)(b * CC + cr) * DD + h * HDD + 16 * n + l15] = acc[n][r] * rlr[r];
    }
  if (g == 0)
    lse[(size_t)bh * CC + q0 + l15] = m + __builtin_amdgcn_logf(l) + 4.0f;  // + log2(H)
}

// ---------------------------------------------------------------------------
// Kernel 3: attn_mean = (1/H) * sum_h softmax_h  (1/H folded into lse).
// Recomputes S per head via MFMA; accumulates over heads in registers.
// No reductions needed (lse known) -> already shuffle-free; just more blocks.
// ---------------------------------------------------------------------------
__global__ __launch_bounds__(256) void attn_mean_kernel(
    const unsigned short* __restrict__ qw, const unsigned short* __restrict__ kw,
    const float* __restrict__ lse, float* __restrict__ amean)
{
  const int blk = blockIdx.x;          // B * (C/64) * 16 = 2048
  const int ks = blk & 15;
  const int qt = (blk >> 4) & 31;
  const int b  = blk >> 9;
  const int wave = threadIdx.x >> 6;
  const int lane = threadIdx.x & 63;
  const int g = lane >> 4, l15 = lane & 15;
  const int q0 = qt * 64 + wave * 16;
  const f32x4 fzero = {0.f, 0.f, 0.f, 0.f};

  f32x4 ap[2][4] = {{fzero, fzero, fzero, fzero}, {fzero, fzero, fzero, fzero}};
  for (int h = 0; h < HH; ++h) {
    const int bh = b * HH + h;
    const unsigned short* qbh = qw + (size_t)bh * CC * HDD;
    const unsigned short* kbh = kw + (size_t)bh * CC * HDD;
    bf16x8 qa[2];
    for (int c = 0; c < 2; ++c)
      qa[c] = *(const bf16x8*)(qbh + (q0 + l15) * HDD + 32 * c + 8 * g);
    float ls[4];
    for (int r = 0; r < 4; ++r) ls[r] = lse[(size_t)bh * CC + q0 + 4 * g + r];
    for (int t = 0; t < 2; ++t) {
      const int kv0 = (ks * 2 + t) * 64;
      f32x4 s[4] = {fzero, fzero, fzero, fzero};
      for (int c = 0; c < 2; ++c)
        for (int n = 0; n < 4; ++n) {
          bf16x8 kf = *(const bf16x8*)(kbh + (kv0 + 16 * n + l15) * HDD + 32 * c + 8 * g);
          s[n] = __builtin_amdgcn_mfma_f32_16x16x32_bf16(qa[c], kf, s[n], 0, 0, 0);
        }
      for (int n = 0; n < 4; ++n)
        for (int r = 0; r < 4; ++r)
          ap[t][n][r] += __builtin_amdgcn_exp2f(s[n][r] - ls[r]);
    }
  }
  for (int t = 0; t < 2; ++t) {
    const int kv0 = (ks * 2 + t) * 64;
    for (int n = 0; n < 4; ++n)
      for (int r = 0; r < 4; ++r)
        amean[(size_t)(b * CC + q0 + 4 * g + r) * CC + kv0 + 16 * n + l15] = ap[t][n][r];
  }
}

extern "C" void kernel_launch(void* const* d_in, const int* in_sizes, int n_in,
                              void* d_out, int out_size, void* d_ws, size_t ws_size,
                              hipStream_t stream) {
  const float* x  = (const float*)d_in[0];
  const float* Wq = (const float*)d_in[1];
  const float* bq = (const float*)d_in[2];
  const float* Wk = (const float*)d_in[3];
  const float* bk = (const float*)d_in[4];
  const float* Wv = (const float*)d_in[5];
  const float* bv = (const float*)d_in[6];
  float* out = (float*)d_out;
  float* amean = out + (size_t)BB * CC * DD;

  const size_t nqkv = (size_t)BB * HH * CC * HDD;
  unsigned short* qws  = (unsigned short*)d_ws;
  unsigned short* kws  = qws + nqkv;
  unsigned short* vtws = kws + nqkv;
  float* lse = (float*)(vtws + nqkv);

  qkv_proj_kernel<<<BB * HH * (CC / 128), 256, 0, stream>>>(
      x, Wq, bq, Wk, bk, Wv, bv, qws, kws, vtws);
  flash_fwd_kernel<<<BB * HH * (CC / 64), 256, 0, stream>>>(
      qws, kws, vtws, out, lse);
  attn_mean_kernel<<<BB * (CC / 64) * 16, 256, 0, stream>>>(
      qws, kws, lse, amean);
}

// Round 3
// 445.930 us; speedup vs baseline: 1.7195x; 1.6495x over previous
//
#include <hip/hip_runtime.h>
#include <hip/hip_bf16.h>

#define BB 4
#define CC 2048
#define DD 1024
#define HH 16
#define HDD 64

typedef __attribute__((ext_vector_type(8))) short bf16x8;
typedef __attribute__((ext_vector_type(4))) float f32x4;
typedef __attribute__((ext_vector_type(4))) unsigned short ushort4_t;

// (1/sqrt(64)) * log2(e): puts scores directly in exp2 domain
#define SCALE_LOG2E 0.18033688011112042f

__device__ __forceinline__ unsigned short f2bf(float f) {
  union { float f; unsigned u; } v; v.f = f;
  unsigned u = v.u;
  return (unsigned short)((u + 0x7fffu + ((u >> 16) & 1u)) >> 16);
}

__device__ __forceinline__ unsigned cvt_pk_bf16(float lo, float hi) {
  unsigned r;
  asm("v_cvt_pk_bf16_f32 %0, %1, %2" : "=v"(r) : "v"(lo), "v"(hi));
  return r;
}

// ---------------------------------------------------------------------------
// Kernel 1: per-head QKV projection.
// q,k stored [B,H,C,HD] bf16 (q pre-scaled by SCALE_LOG2E); v stored
// transposed [B,H,HD,C] bf16 so PV B-operand reads are contiguous.
// ---------------------------------------------------------------------------
__global__ __launch_bounds__(256) void qkv_proj_kernel(
    const float* __restrict__ x,
    const float* __restrict__ Wq, const float* __restrict__ bq,
    const float* __restrict__ Wk, const float* __restrict__ bk,
    const float* __restrict__ Wv, const float* __restrict__ bv,
    unsigned short* __restrict__ qo, unsigned short* __restrict__ ko,
    unsigned short* __restrict__ vto)
{
  const int blk = blockIdx.x;          // B*H*(C/128) = 1024
  const int ct = blk & 15;
  const int h  = (blk >> 4) & 15;
  const int b  = blk >> 8;
  const int wave = threadIdx.x >> 6;
  const int lane = threadIdx.x & 63;
  const int g = lane >> 4, l15 = lane & 15;

  const float* wqh = Wq + h * HDD * HDD;
  const float* wkh = Wk + h * HDD * HDD;
  const float* wvh = Wv + h * HDD * HDD;

  bf16x8 wqf[2][4], wkf[2][4], wvf[2][4];
  for (int c = 0; c < 2; ++c)
    for (int n = 0; n < 4; ++n) {
      const int e = 16 * n + l15;
      const int d0 = 32 * c + 8 * g;
      bf16x8 tq, tk, tv;
      for (int i = 0; i < 8; ++i) {
        tq[i] = (short)f2bf(wqh[(d0 + i) * HDD + e]);
        tk[i] = (short)f2bf(wkh[(d0 + i) * HDD + e]);
        tv[i] = (short)f2bf(wvh[(d0 + i) * HDD + e]);
      }
      wqf[c][n] = tq; wkf[c][n] = tk; wvf[c][n] = tv;
    }
  float bqv[4], bkv[4], bvv[4];
  for (int n = 0; n < 4; ++n) {
    bqv[n] = bq[h * HDD + 16 * n + l15];
    bkv[n] = bk[h * HDD + 16 * n + l15];
    bvv[n] = bv[h * HDD + 16 * n + l15];
  }

  const f32x4 fzero = {0.f, 0.f, 0.f, 0.f};
  const int c0 = ct * 128 + wave * 32;
  const int bh = b * HH + h;

  for (int mt = 0; mt < 2; ++mt) {
    const int crow_a = c0 + mt * 16 + l15;
    bf16x8 xa[2];
    for (int c = 0; c < 2; ++c) {
      const f32x4* xp = (const f32x4*)(x + (size_t)(b * CC + crow_a) * DD + h * HDD + 32 * c + 8 * g);
      f32x4 x0 = xp[0], x1 = xp[1];
      bf16x8 t;
      for (int i = 0; i < 4; ++i) { t[i] = (short)f2bf(x0[i]); t[4 + i] = (short)f2bf(x1[i]); }
      xa[c] = t;
    }
    f32x4 aq[4] = {fzero, fzero, fzero, fzero};
    f32x4 ak[4] = {fzero, fzero, fzero, fzero};
    f32x4 av[4] = {fzero, fzero, fzero, fzero};
    for (int c = 0; c < 2; ++c)
      for (int n = 0; n < 4; ++n) {
        aq[n] = __builtin_amdgcn_mfma_f32_16x16x32_bf16(xa[c], wqf[c][n], aq[n], 0, 0, 0);
        ak[n] = __builtin_amdgcn_mfma_f32_16x16x32_bf16(xa[c], wkf[c][n], ak[n], 0, 0, 0);
        av[n] = __builtin_amdgcn_mfma_f32_16x16x32_bf16(xa[c], wvf[c][n], av[n], 0, 0, 0);
      }
    const int crow_d = c0 + mt * 16 + 4 * g;
    for (int n = 0; n < 4; ++n) {
      const int e = 16 * n + l15;
      ushort4_t vpack;
      for (int r = 0; r < 4; ++r) {
        const int cr = crow_d + r;
        qo[((size_t)bh * CC + cr) * HDD + e] = f2bf((aq[n][r] + bqv[n]) * SCALE_LOG2E);
        ko[((size_t)bh * CC + cr) * HDD + e] = f2bf(ak[n][r] + bkv[n]);
        vpack[r] = f2bf(av[n][r] + bvv[n]);
      }
      *(ushort4_t*)(vto + ((size_t)bh * HDD + e) * CC + crow_d) = vpack;
    }
  }
}

// ---------------------------------------------------------------------------
// Kernel 2: flash attention (out + LSE), swapped QK^T, 32 q-rows per wave,
// explicit 2-deep register pipeline: K double-buffered one tile ahead,
// V issued at iteration top (~400cyc before PV use). sched_barrier(0) pins
// the load block so the scheduler cannot sink loads to their uses (the
// round-1 failure mode: VGPR=60, serialized load-use stalls).
// LDS P-bounce uses pad-72 rows (write 2-way-free, b128 read conflict-free).
// ---------------------------------------------------------------------------
#define KLOAD(DST, KT) do { const int _kv = (KT) * 64;                         \
  _Pragma("unroll") for (int _c = 0; _c < 2; ++_c)                             \
  _Pragma("unroll") for (int _n = 0; _n < 4; ++_n)                             \
    DST[_c][_n] = *(const bf16x8*)(kbh + (_kv + 16 * _n + l15) * HDD + 32 * _c + 8 * g); \
} while (0)

#define VLOAD(DST, KT) do { const int _kv = (KT) * 64;                         \
  _Pragma("unroll") for (int _c = 0; _c < 2; ++_c)                             \
  _Pragma("unroll") for (int _n = 0; _n < 4; ++_n)                             \
    DST[_c][_n] = *(const bf16x8*)(vbh + (16 * _n + l15) * CC + _kv + 32 * _c + 8 * g); \
} while (0)

#define FLASH_TILE(KF) do {                                                    \
  f32x4 s_[2][4];                                                              \
  _Pragma("unroll") for (int h2 = 0; h2 < 2; ++h2)                             \
  _Pragma("unroll") for (int n = 0; n < 4; ++n) s_[h2][n] = fzero;             \
  _Pragma("unroll") for (int c = 0; c < 2; ++c)                                \
  _Pragma("unroll") for (int n = 0; n < 4; ++n) {                              \
    s_[0][n] = __builtin_amdgcn_mfma_f32_16x16x32_bf16(KF[c][n], qb[0][c], s_[0][n], 0, 0, 0); \
    s_[1][n] = __builtin_amdgcn_mfma_f32_16x16x32_bf16(KF[c][n], qb[1][c], s_[1][n], 0, 0, 0); \
  }                                                                            \
  float pm[2], mn[2], rs[2];                                                   \
  _Pragma("unroll") for (int h2 = 0; h2 < 2; ++h2) {                           \
    float a0 = fmaxf(fmaxf(s_[h2][0][0], s_[h2][0][1]), fmaxf(s_[h2][0][2], s_[h2][0][3])); \
    float a1 = fmaxf(fmaxf(s_[h2][1][0], s_[h2][1][1]), fmaxf(s_[h2][1][2], s_[h2][1][3])); \
    float a2 = fmaxf(fmaxf(s_[h2][2][0], s_[h2][2][1]), fmaxf(s_[h2][2][2], s_[h2][2][3])); \
    float a3 = fmaxf(fmaxf(s_[h2][3][0], s_[h2][3][1]), fmaxf(s_[h2][3][2], s_[h2][3][3])); \
    float p_ = fmaxf(fmaxf(a0, a1), fmaxf(a2, a3));                            \
    p_ = fmaxf(p_, __shfl_xor(p_, 16, 64));                                    \
    p_ = fmaxf(p_, __shfl_xor(p_, 32, 64));                                    \
    pm[h2] = p_; mn[h2] = fmaxf(m[h2], p_);                                    \
  }                                                                            \
  const bool keep = __all(fmaxf(pm[0] - m[0], pm[1] - m[1]) <= 8.0f);          \
  if (keep) { mn[0] = m[0]; mn[1] = m[1]; }                                    \
  _Pragma("unroll") for (int h2 = 0; h2 < 2; ++h2) {                           \
    float r_ = 0.f;                                                            \
    _Pragma("unroll") for (int n = 0; n < 4; ++n) {                            \
      float p0 = __builtin_amdgcn_exp2f(s_[h2][n][0] - mn[h2]);                \
      float p1 = __builtin_amdgcn_exp2f(s_[h2][n][1] - mn[h2]);                \
      float p2 = __builtin_amdgcn_exp2f(s_[h2][n][2] - mn[h2]);                \
      float p3 = __builtin_amdgcn_exp2f(s_[h2][n][3] - mn[h2]);                \
      r_ += (p0 + p1) + (p2 + p3);                                             \
      uint2 wv_; wv_.x = cvt_pk_bf16(p0, p1); wv_.y = cvt_pk_bf16(p2, p3);     \
      *(uint2*)(myp[h2] + l15 * 72 + 16 * n + 4 * g) = wv_;                    \
    }                                                                          \
    r_ += __shfl_xor(r_, 16, 64);                                              \
    r_ += __shfl_xor(r_, 32, 64);                                              \
    rs[h2] = r_;                                                               \
  }                                                                            \
  if (keep) { l[0] += rs[0]; l[1] += rs[1]; }                                  \
  else {                                                                       \
    _Pragma("unroll") for (int h2 = 0; h2 < 2; ++h2) {                         \
      const float sc_ = __builtin_amdgcn_exp2f(m[h2] - mn[h2]);                \
      l[h2] = l[h2] * sc_ + rs[h2]; m[h2] = mn[h2];                            \
      float scr_[4];                                                           \
      _Pragma("unroll") for (int r = 0; r < 4; ++r) scr_[r] = __shfl(sc_, 4 * g + r, 64); \
      _Pragma("unroll") for (int n = 0; n < 4; ++n)                            \
      _Pragma("unroll") for (int r = 0; r < 4; ++r) acc[h2][n][r] *= scr_[r];  \
    }                                                                          \
  }                                                                            \
  bf16x8 pa_[2][2];                                                            \
  _Pragma("unroll") for (int h2 = 0; h2 < 2; ++h2)                             \
  _Pragma("unroll") for (int c = 0; c < 2; ++c)                                \
    pa_[h2][c] = *(const bf16x8*)(myp[h2] + l15 * 72 + 32 * c + 8 * g);        \
  _Pragma("unroll") for (int c = 0; c < 2; ++c)                                \
  _Pragma("unroll") for (int n = 0; n < 4; ++n) {                              \
    acc[0][n] = __builtin_amdgcn_mfma_f32_16x16x32_bf16(pa_[0][c], vv[c][n], acc[0][n], 0, 0, 0); \
    acc[1][n] = __builtin_amdgcn_mfma_f32_16x16x32_bf16(pa_[1][c], vv[c][n], acc[1][n], 0, 0, 0); \
  }                                                                            \
} while (0)

__global__ __launch_bounds__(256, 2) void flash_fwd_kernel(
    const unsigned short* __restrict__ qw, const unsigned short* __restrict__ kw,
    const unsigned short* __restrict__ vtw,
    float* __restrict__ out, float* __restrict__ lse)
{
  __shared__ __align__(16) unsigned short plds[4][2][16 * 72];
  const int blk = blockIdx.x;          // B*H*(C/128) = 1024
  const int qt = blk & 15;
  const int h  = (blk >> 4) & 15;
  const int b  = blk >> 8;
  const int wave = threadIdx.x >> 6;
  const int lane = threadIdx.x & 63;
  const int g = lane >> 4, l15 = lane & 15;
  const int bh = b * HH + h;
  const int q0 = qt * 128 + wave * 32;

  const unsigned short* qbh = qw + (size_t)bh * CC * HDD;
  const unsigned short* kbh = kw + (size_t)bh * CC * HDD;
  const unsigned short* vbh = vtw + (size_t)bh * HDD * CC;

  bf16x8 qb[2][2];
  for (int h2 = 0; h2 < 2; ++h2)
    for (int c = 0; c < 2; ++c)
      qb[h2][c] = *(const bf16x8*)(qbh + (q0 + 16 * h2 + l15) * HDD + 32 * c + 8 * g);

  const f32x4 fzero = {0.f, 0.f, 0.f, 0.f};
  f32x4 acc[2][4] = {{fzero, fzero, fzero, fzero}, {fzero, fzero, fzero, fzero}};
  float m[2] = {-1e30f, -1e30f}, l[2] = {0.f, 0.f};
  unsigned short* const myp[2] = {plds[wave][0], plds[wave][1]};

  bf16x8 ka[2][4], kb_[2][4], vv[2][4];
  KLOAD(ka, 0);
  for (int it = 0; it < 16; ++it) {
    const int kt0 = 2 * it;
    VLOAD(vv, kt0);
    KLOAD(kb_, kt0 + 1);
    __builtin_amdgcn_sched_barrier(0);
    FLASH_TILE(ka);
    VLOAD(vv, kt0 + 1);
    KLOAD(ka, (kt0 + 2) & 31);
    __builtin_amdgcn_sched_barrier(0);
    FLASH_TILE(kb_);
  }

  for (int h2 = 0; h2 < 2; ++h2) {
    float rl = __builtin_amdgcn_rcpf(l[h2]);
    float rlr[4];
    for (int r = 0; r < 4; ++r) rlr[r] = __shfl(rl, 4 * g + r, 64);
    for (int n = 0; n < 4; ++n)
      for (int r = 0; r < 4; ++r) {
        const int cr = q0 + 16 * h2 + 4 * g + r;
        out[(size_t)(b * CC + cr) * DD + h * HDD + 16 * n + l15] = acc[h2][n][r] * rlr[r];
      }
  }
  if (g == 0)
    for (int h2 = 0; h2 < 2; ++h2)
      lse[(size_t)bh * CC + q0 + 16 * h2 + l15] =
          m[h2] + __builtin_amdgcn_logf(l[h2]) + 4.0f;  // + log2(H)
}

// ---------------------------------------------------------------------------
// Kernel 3: attn_mean, swapped orientation (lse lane-local, f32x4 stores),
// one 64-kv tile per block, 32 q per wave, pipelined over heads with K/Q/lse
// prefetched one head ahead.
// ---------------------------------------------------------------------------
#define AKLOAD(DST, H) do {                                                    \
  const unsigned short* _kb = kw + (size_t)(b * HH + (H)) * CC * HDD;          \
  _Pragma("unroll") for (int _c = 0; _c < 2; ++_c)                             \
  _Pragma("unroll") for (int _n = 0; _n < 4; ++_n)                             \
    DST[_c][_n] = *(const bf16x8*)(_kb + (kv0 + 16 * _n + l15) * HDD + 32 * _c + 8 * g); \
} while (0)

#define AQLOAD(DST, H) do {                                                    \
  const unsigned short* _qb = qw + (size_t)(b * HH + (H)) * CC * HDD;          \
  _Pragma("unroll") for (int _h2 = 0; _h2 < 2; ++_h2)                          \
  _Pragma("unroll") for (int _c = 0; _c < 2; ++_c)                             \
    DST[_h2][_c] = *(const bf16x8*)(_qb + (q0 + 16 * _h2 + l15) * HDD + 32 * _c + 8 * g); \
} while (0)

#define ALLOAD(DST, H) do {                                                    \
  const size_t _o = (size_t)(b * HH + (H)) * CC + q0 + l15;                    \
  DST[0] = lse[_o]; DST[1] = lse[_o + 16];                                     \
} while (0)

#define ASTEP(KF, QF, LS) do {                                                 \
  f32x4 s_[2][4];                                                              \
  _Pragma("unroll") for (int h2 = 0; h2 < 2; ++h2)                             \
  _Pragma("unroll") for (int n = 0; n < 4; ++n) s_[h2][n] = fzero;             \
  _Pragma("unroll") for (int c = 0; c < 2; ++c)                                \
  _Pragma("unroll") for (int n = 0; n < 4; ++n) {                              \
    s_[0][n] = __builtin_amdgcn_mfma_f32_16x16x32_bf16(KF[c][n], QF[0][c], s_[0][n], 0, 0, 0); \
    s_[1][n] = __builtin_amdgcn_mfma_f32_16x16x32_bf16(KF[c][n], QF[1][c], s_[1][n], 0, 0, 0); \
  }                                                                            \
  _Pragma("unroll") for (int h2 = 0; h2 < 2; ++h2)                             \
  _Pragma("unroll") for (int n = 0; n < 4; ++n)                                \
  _Pragma("unroll") for (int r = 0; r < 4; ++r)                                \
    ap[h2][n][r] += __builtin_amdgcn_exp2f(s_[h2][n][r] - LS[h2]);             \
} while (0)

__global__ __launch_bounds__(256, 2) void attn_mean_kernel(
    const unsigned short* __restrict__ qw, const unsigned short* __restrict__ kw,
    const float* __restrict__ lse, float* __restrict__ amean)
{
  const int blk = blockIdx.x;          // B * (C/128) * 32 = 2048
  const int ks = blk & 31;
  const int qt = (blk >> 5) & 15;
  const int b  = blk >> 9;
  const int wave = threadIdx.x >> 6;
  const int lane = threadIdx.x & 63;
  const int g = lane >> 4, l15 = lane & 15;
  const int q0 = qt * 128 + wave * 32;
  const int kv0 = ks * 64;
  const f32x4 fzero = {0.f, 0.f, 0.f, 0.f};

  f32x4 ap[2][4] = {{fzero, fzero, fzero, fzero}, {fzero, fzero, fzero, fzero}};
  bf16x8 ka[2][4], kb_[2][4], qa[2][2], qn[2][2];
  float lsa[2], lsb[2];

  AKLOAD(ka, 0); AQLOAD(qa, 0); ALLOAD(lsa, 0);
  for (int hh = 0; hh < 8; ++hh) {
    const int h = 2 * hh;
    AKLOAD(kb_, h + 1); AQLOAD(qn, h + 1); ALLOAD(lsb, h + 1);
    __builtin_amdgcn_sched_barrier(0);
    ASTEP(ka, qa, lsa);
    AKLOAD(ka, (h + 2) & 15); AQLOAD(qa, (h + 2) & 15); ALLOAD(lsa, (h + 2) & 15);
    __builtin_amdgcn_sched_barrier(0);
    ASTEP(kb_, qn, lsb);
  }

  for (int h2 = 0; h2 < 2; ++h2)
    for (int n = 0; n < 4; ++n)
      *(f32x4*)(amean + (size_t)(b * CC + q0 + 16 * h2 + l15) * CC + kv0 + 16 * n + 4 * g) = ap[h2][n];
}

extern "C" void kernel_launch(void* const* d_in, const int* in_sizes, int n_in,
                              void* d_out, int out_size, void* d_ws, size_t ws_size,
                              hipStream_t stream) {
  const float* x  = (const float*)d_in[0];
  const float* Wq = (const float*)d_in[1];
  const float* bq = (const float*)d_in[2];
  const float* Wk = (const float*)d_in[3];
  const float* bk = (const float*)d_in[4];
  const float* Wv = (const float*)d_in[5];
  const float* bv = (const float*)d_in[6];
  float* out = (float*)d_out;
  float* amean = out + (size_t)BB * CC * DD;

  const size_t nqkv = (size_t)BB * HH * CC * HDD;
  unsigned short* qws  = (unsigned short*)d_ws;
  unsigned short* kws  = qws + nqkv;
  unsigned short* vtws = kws + nqkv;
  float* lse = (float*)(vtws + nqkv);

  qkv_proj_kernel<<<BB * HH * (CC / 128), 256, 0, stream>>>(
      x, Wq, bq, Wk, bk, Wv, bv, qws, kws, vtws);
  flash_fwd_kernel<<<BB * HH * (CC / 128), 256, 0, stream>>>(
      qws, kws, vtws, out, lse);
  attn_mean_kernel<<<BB * (CC / 128) * 32, 256, 0, stream>>>(
      qws, kws, lse, amean);
}